// Round 18
// baseline (88.453 us; speedup 1.0000x reference)
//
#include <hip/hip_runtime.h>
#include <hip/hip_bf16.h>

#define IN_H  224
#define IN_W  224
#define OUT_H 218
#define OUT_W 218
#define NCH   64
#define PLANE (OUT_H * OUT_W)
#define RSH   464            // bf16 tile row stride (ushorts)
#define CP1   232            // copy1 offset within row (ushorts)
#define NROW  4              // output rows per block
#define NYB   55             // ceil(218/4)
#define NMT   4              // channel groups of 16
#define OCH   876            // obuf per-plane stride (872 data + 4 pad)
#define NBLK  (32 * NMT * NYB)   // 7040 = 8 XCDs * 880 -> bijective chunk map

typedef short bf16x8 __attribute__((ext_vector_type(8)));
typedef float f32x4  __attribute__((ext_vector_type(4)));

__device__ inline unsigned int f2bf(float f) {   // RNE f32 -> bf16 (cold path)
    unsigned int u = __builtin_bit_cast(unsigned int, f);
    return (u + 0x7fffu + ((u >> 16) & 1u)) >> 16;
}

__device__ inline unsigned int pk2(float lo, float hi) {  // v_cvt_pk path (proven R12+)
    __hip_bfloat162 h2 = __float22bfloat162_rn(make_float2(lo, hi));
    unsigned int u;
    __builtin_memcpy(&u, &h2, sizeof(u));
    return u;
}

// lgkm-only barrier: LDS ops retired; global stores stay in flight (no vmcnt drain).
__device__ inline void bar_lgkm() {
    asm volatile("s_waitcnt lgkmcnt(0)" ::: "memory");
    __builtin_amdgcn_sched_barrier(0);
    __builtin_amdgcn_s_barrier();
    __builtin_amdgcn_sched_barrier(0);
}

// Pack weights into MFMA A-fragments (bf16, 7x7 zero-padded to 8x8). Verified R5-R17.
// [fc = mt*2+kt][lane]: ch = 16*mt + (lane&15), dy = 4*kt + (lane>>4),
// word j = {dx=2j (lo), dx=2j+1 (hi)}.
__global__ __launch_bounds__(512) void repack_w(const float* __restrict__ wgt,
                                                unsigned int* __restrict__ wa) {
    const int t    = threadIdx.x;
    const int lane = t & 63;
    const int fc   = t >> 6;
    const int mt   = fc >> 1, kt = fc & 1;
    const int ch   = 16 * mt + (lane & 15);
    const int dy   = 4 * kt + (lane >> 4);
    unsigned int w[4];
#pragma unroll
    for (int j = 0; j < 4; ++j) {
        float lo = (dy < 7 && 2 * j     < 7) ? wgt[ch * 49 + dy * 7 + 2 * j]     : 0.f;
        float hi = (dy < 7 && 2 * j + 1 < 7) ? wgt[ch * 49 + dy * 7 + 2 * j + 1] : 0.f;
        w[j] = f2bf(lo) | (f2bf(hi) << 16);
    }
    reinterpret_cast<uint4*>(wa)[fc * 64 + lane] = make_uint4(w[0], w[1], w[2], w[3]);
}

// R17 structure (86.7us) + half-split store overlap: compute r01 -> bar ->
// issue s01 -> compute r23 (hides under s01 drain; disjoint obuf) -> lgkm-bar
// (stores stay in flight) -> s23. Plus float4 staging (580 items, uint2 writes).
__global__ __launch_bounds__(512) void conv7x7_row(
    const float* __restrict__ in,
    const unsigned int* __restrict__ wa,
    float* __restrict__ out)
{
    __shared__ unsigned short tbf[10 * RSH];  //  9280 B: bf16 rows, dual copy
    __shared__ float obuf[16 * OCH];          // 56064 B: 16 planes x (4x218)

    const int tid  = threadIdx.x;
    const int lane = tid & 63;
    const int wid  = tid >> 6;
    const int g    = lane >> 4;
    const int c    = lane & 15;

    // Chunked XCD map (bijective: 7040 = 8*880), y-innermost.
    const int bid  = blockIdx.x;
    const int rank = (bid & 7) * (NBLK / 8) + (bid >> 3);
    const int n    = rank / (NMT * NYB);
    const int rem  = rank - n * (NMT * NYB);
    const int mt   = rem / NYB;
    const int yb   = rem - mt * NYB;
    const int y0   = yb * NROW;           // <= 216

    // ---- stationary A-fragments ----
    union AB { uint4 u; bf16x8 v; };
    AB af[2];
    const uint4* wa4 = reinterpret_cast<const uint4*>(wa);
#pragma unroll
    for (int kt = 0; kt < 2; ++kt) af[kt].u = wa4[(mt * 2 + kt) * 64 + lane];

    // ---- stage 10 rows, bf16 dual-copy, float4 loads, pad folded in ----
    const float* inb = in + (size_t)n * (IN_H * IN_W);
    for (int idx = tid; idx < 10 * 58; idx += 512) {
        int r = idx / 58, c4 = idx - r * 58;            // cols 4c4..4c4+3 (<=231)
        int iny = min(y0 + r, IN_H - 1);
        const float* rp = inb + iny * IN_W;
        float4 v = (c4 < 56) ? *reinterpret_cast<const float4*>(rp + 4 * c4)
                             : make_float4(0.f, 0.f, 0.f, 0.f);
        float nx = (c4 < 55) ? rp[4 * c4 + 4] : 0.f;    // elem 224.. = pad 0
        uint2 w0 = make_uint2(pk2(v.x, v.y), pk2(v.z, v.w));        // copy0
        uint2 w1 = make_uint2(pk2(v.y, v.z), pk2(v.w, nx));         // copy1 (+1 shift)
        *reinterpret_cast<uint2*>(&tbf[r * RSH + 4 * c4])       = w0;
        *reinterpret_cast<uint2*>(&tbf[r * RSH + CP1 + 4 * c4]) = w1;
    }
    __syncthreads();

    const int sh = c & 1;

    // ---- compute macro: one (row r, strip) iteration ----
#define CONV_ITER(kk)                                                          \
    {                                                                          \
        const int r  = (kk) / 14;                                              \
        const int x0 = 16 * ((kk) - 14 * r);                                   \
        const int e0 = x0 + c - sh;                                            \
        AB bf[2];                                                              \
        _Pragma("unroll")                                                      \
        for (int kt = 0; kt < 2; ++kt) {                                       \
            const int row = min(r + 4 * kt + g, 9);                            \
            const unsigned int* p = reinterpret_cast<const unsigned int*>(     \
                &tbf[row * RSH + sh * CP1 + e0]);                              \
            union { unsigned int u[4]; uint4 q; } bb;                          \
            bb.u[0] = p[0]; bb.u[1] = p[1]; bb.u[2] = p[2]; bb.u[3] = p[3];    \
            bf[kt].u = bb.q;                                                   \
        }                                                                      \
        f32x4 acc = {0.f, 0.f, 0.f, 0.f};                                      \
        acc = __builtin_amdgcn_mfma_f32_16x16x32_bf16(af[0].v, bf[0].v, acc, 0, 0, 0); \
        acc = __builtin_amdgcn_mfma_f32_16x16x32_bf16(af[1].v, bf[1].v, acc, 0, 0, 0); \
        if (x0 + c < OUT_W) {                                                  \
            _Pragma("unroll")                                                  \
            for (int rr = 0; rr < 4; ++rr)                                     \
                obuf[(4 * g + rr) * OCH + r * OUT_W + x0 + c] = acc[rr];       \
        }                                                                      \
    }

    // ---- store macro: this wave's 2 planes, float4 runs ----
#define STORE_HALF(srcoff, n4)                                                 \
    {                                                                          \
        const size_t base = ((size_t)(n * NCH + 16 * mt)) * PLANE              \
                          + (size_t)y0 * OUT_W + (srcoff);                     \
        _Pragma("unroll")                                                      \
        for (int i = 0; i < 2; ++i) {                                          \
            const int p = 2 * wid + i;                                         \
            const float* src = &obuf[p * OCH + (srcoff)];                      \
            float* dst = out + base + (size_t)p * PLANE;                       \
            _Pragma("unroll")                                                  \
            for (int j = 0; j < 2; ++j) {                                      \
                int idx = 64 * j + lane;                                       \
                if (idx < (n4))                                                \
                    *reinterpret_cast<float4*>(dst + 4 * idx) =                \
                        *reinterpret_cast<const float4*>(src + 4 * idx);       \
            }                                                                  \
        }                                                                      \
    }

    // phase 1: compute rows 0-1 (iters 0..27)
    for (int k = wid; k < 28; k += 8) CONV_ITER(k)
    bar_lgkm();                          // obuf r01 complete (no stores yet)

    // phase 2: issue stores rows 0-1, then immediately compute rows 2-3.
    // c23 writes obuf floats 436..871 — disjoint from s01's reads (0..435).
    STORE_HALF(0, 109)
    for (int k = 28 + wid; k < 56; k += 8) CONV_ITER(k)
    bar_lgkm();                          // obuf r23 complete; s01 stays in flight

    // phase 3: store rows 2-3 (skip at the y0=216 tail: only 2 valid rows)
    if (y0 + 2 < OUT_H) STORE_HALF(436, 109)

#undef CONV_ITER
#undef STORE_HALF
}

extern "C" void kernel_launch(void* const* d_in, const int* in_sizes, int n_in,
                              void* d_out, int out_size, void* d_ws, size_t ws_size,
                              hipStream_t stream) {
    const float* in  = (const float*)d_in[0];
    const float* wgt = (const float*)d_in[1];
    float* out = (float*)d_out;
    unsigned int* wa = (unsigned int*)d_ws;   // 8*64*16 = 8192 B

    repack_w<<<1, 512, 0, stream>>>(wgt, wa);
    conv7x7_row<<<NBLK, 512, 0, stream>>>(in, wa, out);
}